// Round 11
// baseline (35.936 us; speedup 1.0000x reference)
//
#include <hip/hip_runtime.h>
#include <math.h>

constexpr int kD   = 128;
constexpr int kE   = 256;
constexpr int kTok = 2048;

// ---------------- K1: gate, 8 tokens/block ----------------------------------
// 256 blocks x 1024 threads (16 waves/CU). Thread = (token-group tg = t>>8,
// expert ge = t&255); each thread owns 2 tokens (2tg, 2tg+1). Per-token
// reduction: 64-lane butterfly + 4-wave LDS combine (waves tg*4..tg*4+3).
__global__ __launch_bounds__(1024) void k_gate8(
    const float* __restrict__ x, const float* __restrict__ gate_w,
    const float* __restrict__ gate_b,
    float2* __restrict__ tokinfo, int* __restrict__ top2)
{
    const int b  = blockIdx.x;
    const int t  = threadIdx.x;
    const int ge = t & 255;
    const int tg = t >> 8;          // 0..3
    const int ln = t & 63;
    const int wg = (t >> 6) & 3;    // wave within token-group
    const int tok0 = b * 8;
    const int j0 = tg * 2, j1 = tg * 2 + 1;

    __shared__ float xsT[kD][10];   // stride 10: float2-aligned, spread banks
    __shared__ float partf[8][4];
    __shared__ int   parti[8][4];
    __shared__ float pv0s[8];
    __shared__ int   pi0s[8];

    // load 8 x rows, transposed (one element per thread)
    {
        const int row = t >> 7, d = t & 127;
        xsT[d][row] = x[(size_t)(tok0 + row) * kD + d];
    }
    __syncthreads();

    // logits for 2 tokens
    const float bias = gate_b[ge];
    float lg0 = bias, lg1 = bias;
    #pragma unroll 8
    for (int d = 0; d < kD; ++d) {
        const float w = gate_w[d * kE + ge];
        const float2 xv = *(const float2*)&xsT[d][tg * 2];   // broadcast
        lg0 = fmaf(xv.x, w, lg0);
        lg1 = fmaf(xv.y, w, lg1);
    }

    // ---- max ----
    float m0 = lg0, m1 = lg1;
    #pragma unroll
    for (int s = 1; s < 64; s <<= 1) {
        m0 = fmaxf(m0, __shfl_xor(m0, s));
        m1 = fmaxf(m1, __shfl_xor(m1, s));
    }
    if (ln == 0) { partf[j0][wg] = m0; partf[j1][wg] = m1; }
    __syncthreads();
    const float mx0 = fmaxf(fmaxf(partf[j0][0], partf[j0][1]),
                            fmaxf(partf[j0][2], partf[j0][3]));
    const float mx1 = fmaxf(fmaxf(partf[j1][0], partf[j1][1]),
                            fmaxf(partf[j1][2], partf[j1][3]));
    __syncthreads();

    // ---- sum of exp ----
    const float ex0 = __expf(lg0 - mx0), ex1 = __expf(lg1 - mx1);
    float s0 = ex0, s1 = ex1;
    #pragma unroll
    for (int s = 1; s < 64; s <<= 1) {
        s0 += __shfl_xor(s0, s);
        s1 += __shfl_xor(s1, s);
    }
    if (ln == 0) { partf[j0][wg] = s0; partf[j1][wg] = s1; }
    __syncthreads();
    const float tot0 = partf[j0][0] + partf[j0][1] + partf[j0][2] + partf[j0][3];
    const float tot1 = partf[j1][0] + partf[j1][1] + partf[j1][2] + partf[j1][3];
    const float p0 = ex0 / tot0, p1 = ex1 / tot1;
    __syncthreads();

    // ---- argmax pass 1 (ties -> lower index) ----
    float v0 = p0, v1 = p1; int ix0 = ge, ix1 = ge;
    #pragma unroll
    for (int s = 1; s < 64; s <<= 1) {
        const float o0 = __shfl_xor(v0, s); const int q0 = __shfl_xor(ix0, s);
        if (o0 > v0 || (o0 == v0 && q0 < ix0)) { v0 = o0; ix0 = q0; }
        const float o1 = __shfl_xor(v1, s); const int q1 = __shfl_xor(ix1, s);
        if (o1 > v1 || (o1 == v1 && q1 < ix1)) { v1 = o1; ix1 = q1; }
    }
    if (ln == 0) {
        partf[j0][wg] = v0; parti[j0][wg] = ix0;
        partf[j1][wg] = v1; parti[j1][wg] = ix1;
    }
    __syncthreads();
    if (t < 8) {
        float bv = partf[t][0]; int bi = parti[t][0];
        #pragma unroll
        for (int w = 1; w < 4; ++w) {
            const float ov = partf[t][w]; const int oi = parti[t][w];
            if (ov > bv || (ov == bv && oi < bi)) { bv = ov; bi = oi; }
        }
        pv0s[t] = bv; pi0s[t] = bi;
    }
    __syncthreads();

    // ---- argmax pass 2 (mask winner) ----
    v0 = (ge == pi0s[j0]) ? -INFINITY : p0; ix0 = ge;
    v1 = (ge == pi0s[j1]) ? -INFINITY : p1; ix1 = ge;
    #pragma unroll
    for (int s = 1; s < 64; s <<= 1) {
        const float o0 = __shfl_xor(v0, s); const int q0 = __shfl_xor(ix0, s);
        if (o0 > v0 || (o0 == v0 && q0 < ix0)) { v0 = o0; ix0 = q0; }
        const float o1 = __shfl_xor(v1, s); const int q1 = __shfl_xor(ix1, s);
        if (o1 > v1 || (o1 == v1 && q1 < ix1)) { v1 = o1; ix1 = q1; }
    }
    if (ln == 0) {
        partf[j0][wg] = v0; parti[j0][wg] = ix0;
        partf[j1][wg] = v1; parti[j1][wg] = ix1;
    }
    __syncthreads();
    if (t < 8) {
        float bv = partf[t][0]; int bi = parti[t][0];
        #pragma unroll
        for (int w = 1; w < 4; ++w) {
            const float ov = partf[t][w]; const int oi = parti[t][w];
            if (ov > bv || (ov == bv && oi < bi)) { bv = ov; bi = oi; }
        }
        const int tok = tok0 + t;
        const float va = pv0s[t], vb = bv;
        const float den = va + vb + 1e-6f;
        tokinfo[tok] = make_float2(va / den, vb / den);
        top2[tok] = pi0s[t] | (bi << 8);
    }
}

// ---------------- K2: expert-grouped matvecs, 4-entry register-blocked ------
// R10-proven version, byte-identical.
__global__ __launch_bounds__(1024) void k_expert(
    const float* __restrict__ x, const float* __restrict__ expert_w,
    const int* __restrict__ top2, float* __restrict__ ybuf)
{
    const int e  = blockIdx.x >> 1;
    const int hf = blockIdx.x & 1;
    const int t  = threadIdx.x;

    __shared__ float W[kD][64];    // 32 KB
    __shared__ float xs[64][kD];   // 32 KB
    __shared__ int   llist[kTok];  // 8 KB
    __shared__ int   lcount;

    if (t == 0) lcount = 0;
    __syncthreads();

    #pragma unroll
    for (int k = 0; k < 2; ++k) {
        const int i = k * 1024 + t;
        const int pk = top2[i];
        if ((pk & 255) == e)        llist[atomicAdd(&lcount, 1)] = i * 2;
        if (((pk >> 8) & 255) == e) llist[atomicAdd(&lcount, 1)] = i * 2 + 1;
    }

    {
        const float* Wg = expert_w + (size_t)e * kD * kD + hf * 64;
        #pragma unroll
        for (int k = 0; k < 2; ++k) {
            const int f  = k * 1024 + t;
            const int r  = f >> 4;
            const int c4 = (f & 15) * 4;
            *(float4*)&W[r][c4] = *(const float4*)&Wg[(size_t)r * kD + c4];
        }
    }
    __syncthreads();
    const int n = lcount;

    const int wv = t >> 6, ln = t & 63;
    for (int base = 0; base < n; base += 64) {
        const int m = min(64, n - base);
        for (int i = t; i < m * kD; i += 1024) {
            const int row = i >> 7, d = i & 127;
            const int ev = llist[base + row];
            xs[row][d] = x[(size_t)(ev >> 1) * kD + d];
        }
        __syncthreads();

        const int i0 = base + wv * 4;
        if (i0 < n) {
            const int r0 = wv * 4;
            const int cnt = min(4, n - i0);
            float a0 = 0.f, a1 = 0.f, a2 = 0.f, a3 = 0.f;
            #pragma unroll 8
            for (int d = 0; d < kD; ++d) {
                const float w = W[d][ln];
                a0 = fmaf(xs[r0 + 0][d], w, a0);
                a1 = fmaf(xs[r0 + 1][d], w, a1);
                a2 = fmaf(xs[r0 + 2][d], w, a2);
                a3 = fmaf(xs[r0 + 3][d], w, a3);
            }
            {
                const int ev0 = llist[i0];
                ybuf[((size_t)(ev0 >> 1) * 2 + (ev0 & 1)) * kD + hf * 64 + ln] = a0;
            }
            if (cnt > 1) {
                const int ev1 = llist[i0 + 1];
                ybuf[((size_t)(ev1 >> 1) * 2 + (ev1 & 1)) * kD + hf * 64 + ln] = a1;
            }
            if (cnt > 2) {
                const int ev2 = llist[i0 + 2];
                ybuf[((size_t)(ev2 >> 1) * 2 + (ev2 & 1)) * kD + hf * 64 + ln] = a2;
            }
            if (cnt > 3) {
                const int ev3 = llist[i0 + 3];
                ybuf[((size_t)(ev3 >> 1) * 2 + (ev3 & 1)) * kD + hf * 64 + ln] = a3;
            }
        }
        __syncthreads();
    }
}

// ---------------- K3: combine + SwiGLU + consensus, 8 tokens/block ----------
// 256 blocks x 1024 threads (16 waves/CU). Thread = (path h, token-pair jp,
// output o); 2 tokens per thread (jp, jp+4).
__global__ __launch_bounds__(1024) void k_swiglu8(
    const float* __restrict__ ybuf, const float2* __restrict__ tokinfo,
    const float* __restrict__ w1m, const float* __restrict__ b1,
    const float* __restrict__ w2m, const float* __restrict__ b2,
    float* __restrict__ out_avg, float* __restrict__ out_cons)
{
    const int b = blockIdx.x;
    const int t = threadIdx.x;
    const int tok0 = b * 8;

    __shared__ float  ys[8][2][kD];   // 8 KB
    __shared__ float  wavT[kD][9];    // stride 9: bank-spread
    __shared__ float  vv[8][kD];      // 4 KB
    __shared__ float  os[8][kD];      // 4 KB
    __shared__ float2 ti[8];
    __shared__ float  cparts[8][2];

    if (t < 512)
        ((float4*)&ys[0][0][0])[t] =
            ((const float4*)&ybuf[(size_t)tok0 * 2 * kD])[t];
    if (t < 8) ti[t] = tokinfo[tok0 + t];
    __syncthreads();

    // combine: weighted avg, transposed
    {
        const int j = t >> 7, o = t & 127;
        const float2 w = ti[j];
        wavT[o][j] = w.x * ys[j][0][o] + w.y * ys[j][1][o];
    }
    __syncthreads();

    // SwiGLU matvecs: h = path, jp = token-pair, o = output
    const int h = t >> 9, rem = t & 511, jp = rem >> 7, o = rem & 127;
    const float* Wm = h ? w2m : w1m;
    const float bias = h ? b2[o] : b1[o];
    float a0 = bias, a1 = bias;
    #pragma unroll 8
    for (int d = 0; d < kD; ++d) {
        const float w = Wm[d * kD + o];
        a0 = fmaf(wavT[d][jp],     w, a0);    // broadcast
        a1 = fmaf(wavT[d][jp + 4], w, a1);    // broadcast
    }
    if (h) { vv[jp][o] = a0; vv[jp + 4][o] = a1; }
    __syncthreads();
    if (!h) {
        const float r0 = a0 * (1.f / (1.f + __expf(-a0))) * vv[jp][o];
        const float r1 = a1 * (1.f / (1.f + __expf(-a1))) * vv[jp + 4][o];
        os[jp][o] = r0;
        os[jp + 4][o] = r1;
        out_avg[(size_t)(tok0 + jp) * kD + o]     = r0;
        out_avg[(size_t)(tok0 + jp + 4) * kD + o] = r1;
    }
    __syncthreads();

    // variance -> consensus: 16 waves, 2 waves/token
    {
        const int wv = t >> 6, ln = t & 63;
        const int tk = wv >> 1;
        const int o2 = (wv & 1) * 64 + ln;
        const float2 w = ti[tk];
        const float ot = os[tk][o2];
        const float d0 = ys[tk][0][o2] - ot;
        const float d1 = ys[tk][1][o2] - ot;
        float s = w.x * d0 * d0 + w.y * d1 * d1;
        #pragma unroll
        for (int sft = 1; sft < 64; sft <<= 1) s += __shfl_xor(s, sft);
        if (ln == 0) cparts[tk][wv & 1] = s;
    }
    __syncthreads();
    if (t < 8)
        out_cons[tok0 + t] = __expf(-(cparts[t][0] + cparts[t][1]) * (1.0f / (float)kD));
}

extern "C" void kernel_launch(void* const* d_in, const int* in_sizes, int n_in,
                              void* d_out, int out_size, void* d_ws, size_t ws_size,
                              hipStream_t stream) {
    const float*  x        = (const float*)d_in[0];
    const float*  gate_w   = (const float*)d_in[1];
    const float*  gate_b   = (const float*)d_in[2];
    const float*  expert_w = (const float*)d_in[3];
    const float*  w1m      = (const float*)d_in[4];
    const float*  b1       = (const float*)d_in[5];
    const float*  w2m      = (const float*)d_in[6];
    const float*  b2       = (const float*)d_in[7];

    float* out_avg  = (float*)d_out;
    float* out_cons = out_avg + (size_t)kTok * kD;

    char*   ws      = (char*)d_ws;
    float2* tokinfo = (float2*)ws;                 // 16 KB
    int*    top2    = (int*)(ws + 16384);          // 8 KB
    float*  ybuf    = (float*)(ws + 32768);        // 2 MB

    k_gate8  <<<kTok / 8, 1024, 0, stream>>>(x, gate_w, gate_b, tokinfo, top2);
    k_expert <<<kE * 2,   1024, 0, stream>>>(x, expert_w, top2, ybuf);
    k_swiglu8<<<kTok / 8, 1024, 0, stream>>>(ybuf, tokinfo, w1m, b1, w2m, b2, out_avg, out_cons);
}